// Round 2
// baseline (85.835 us; speedup 1.0000x reference)
//
#include <hip/hip_runtime.h>

// E2M1 (MXFP4-style) activation quantizer, block size 32, LAYER_MAX = 6.0.
// Outputs concatenated in d_out as float32:
//   [0, N)        x_deq
//   [N, 2N)       encoded (values 0..15, stored as float)
//   [2N, 2N+N/32) scale_uint8 (values 0..255, stored as float)

constexpr int TPB = 256;

__global__ __launch_bounds__(TPB) void e2m1_quant_kernel(
    const float* __restrict__ x,
    float* __restrict__ xdeq,
    float* __restrict__ enc,
    float* __restrict__ scl,
    int n4)
{
    const int tid    = blockIdx.x * TPB + threadIdx.x;
    const int stride = gridDim.x * TPB;

    for (int i = tid; i < n4; i += stride) {
        const float4 v = reinterpret_cast<const float4*>(x)[i];

        // per-lane amax of 4 elems, then reduce across the 8-lane group
        // (8 lanes x 4 elems = one 32-element quant block)
        float a = fmaxf(fmaxf(fabsf(v.x), fabsf(v.y)),
                        fmaxf(fabsf(v.z), fabsf(v.w)));
        a = fmaxf(a, __shfl_xor(a, 1, 8));
        a = fmaxf(a, __shfl_xor(a, 2, 8));
        a = fmaxf(a, __shfl_xor(a, 4, 8));

        // e8m0 = ceil(max(log2(amax/6), -127)), computed exactly:
        // d = f * 2^e with f in [0.5,1)  =>  ceil(log2 d) = e-1 if f==0.5 else e
        const float d = a / 6.0f;   // IEEE division to match numpy rounding
        int e8m0 = -127;
        if (d > 0.0f) {
            int e;
            const float f = frexpf(d, &e);
            e8m0 = (f == 0.5f) ? (e - 1) : e;
            if (e8m0 < -127) e8m0 = -127;
        }

        // scale = 2^e8m0 (power of two -> multiplies below are exact).
        // e8m0 == -127 is the subnormal 0x00400000.
        const float rscale = __uint_as_float(((unsigned)(127 - e8m0)) << 23); // 2^-e8m0
        const float scale  = (e8m0 <= -127)
                               ? __uint_as_float(0x00400000u)
                               : __uint_as_float(((unsigned)(e8m0 + 127)) << 23);

        float4 dq, ef;

        auto enc1 = [&](float xv, float& dqo, float& efo) {
            const float xn  = xv * rscale;        // exact: power-of-2 scale
            const float axn = fabsf(xn);
            const int ord = (axn > 0.25f) + (axn > 0.75f) + (axn > 1.25f) +
                            (axn > 1.75f) + (axn > 2.5f)  + (axn > 3.5f) +
                            (axn > 5.0f);
            // E2M1 value table {0,0.5,1,1.5,2,3,4,6} without runtime-indexed array
            const float m = (ord <= 4) ? (float)ord * 0.5f
                             : (ord == 5 ? 3.0f : (ord == 6 ? 4.0f : 6.0f));
            const bool pos = xn > 0.0f;           // sign_bit = 1 for xn <= 0
            efo = (float)(pos ? ord : ord + 8);
            dqo = (pos ? m : -m) * scale;
        };

        enc1(v.x, dq.x, ef.x);
        enc1(v.y, dq.y, ef.y);
        enc1(v.z, dq.z, ef.z);
        enc1(v.w, dq.w, ef.w);

        reinterpret_cast<float4*>(xdeq)[i] = dq;
        reinterpret_cast<float4*>(enc)[i]  = ef;
        if ((i & 7) == 0)                    // first lane of each 8-lane group
            scl[i >> 3] = (float)(e8m0 + 127);
    }
}

extern "C" void kernel_launch(void* const* d_in, const int* in_sizes, int n_in,
                              void* d_out, int out_size, void* d_ws, size_t ws_size,
                              hipStream_t stream) {
    const float* x = (const float*)d_in[0];
    float* out = (float*)d_out;

    const int n  = in_sizes[0];        // 4096*8192
    const int n4 = n / 4;

    float* xdeq = out;
    float* enc  = out + (size_t)n;
    float* scl  = out + 2 * (size_t)n;

    int blocks = (n4 + TPB - 1) / TPB;
    if (blocks > 2048) blocks = 2048;  // grid-stride the rest (G11)

    e2m1_quant_kernel<<<blocks, TPB, 0, stream>>>(x, xdeq, enc, scl, n4);
}